// Round 5
// baseline (104.530 us; speedup 1.0000x reference)
//
#include <hip/hip_runtime.h>

// Chamfer-with-normals, B=8, C=6 (3 pos + 3 nrm), N=4096, fp32.
// d[i][j] = |ap_i|^2 + |bp_j|^2 - 2 ap_i.bp_j + W*(1 - bn_i.an_j)
// (cross-indexed normals: row i uses b's normal, col j uses a's — verified, absmax 0).
//
// R5: R4's min kernel was ADDITIVELY bound: VALU 53.2k cyc + LDS-broadcast 49.2k cyc
// ≈ 94% of the measured 108.7k cyc/CU — ds_read_b128 requests serialize against
// VALU issue. Fix: col stream moves to broadcast VECTOR global loads (L1-resident
// 4KB/chunk, 1 transaction per request since all 64 lanes hit the same address).
// Compiler would scalarize a uniform address into s_load (R2's 72us failure) —
// an opaque divergent zero from inline asm forces the vector path.
// Partial buffer (8MB traffic) replaced by exact per-row atomicMin on
// monotone-mapped u32 keys (256KB table); sum kernel reads only the table.
// VALU floor: 104 insts / col-pair -> 53.2k cyc/CU = 22.2 us.

constexpr int   NPTS   = 4096;
constexpr int   CPB    = 6;
constexpr int   BATCH  = 8;
constexpr float W      = 0.001f;
constexpr int   CHUNKS = 32;
constexpr int   TJ     = NPTS / CHUNKS;   // 128 cols per block

// Monotone float <-> u32 key: preserves total order; u32-min == float-min (no NaNs here).
__device__ inline unsigned fkey(float x) {
    unsigned b = __float_as_uint(x);
    return b ^ ((b >> 31) ? 0xFFFFFFFFu : 0x80000000u);
}
__device__ inline float funkey(unsigned k) {
    return __uint_as_float(k ^ ((k >> 31) ? 0x80000000u : 0xFFFFFFFFu));
}

// colpack: {qx,qy,qz,nx, ny,nz,|q|^2+W, 0} per column; also inits key table to
// "+inf" (0xFFFFFFFF = max key) and zeroes out[0] (d_out is re-poisoned to 0xAA).
__global__ __launch_bounds__(256) void prep_kernel(
    const float* __restrict__ A, const float* __restrict__ B,
    float* __restrict__ colpack, unsigned* __restrict__ table,
    float* __restrict__ out)
{
    const int g = blockIdx.x * 256 + threadIdx.x;    // 0 .. 2*BATCH*NPTS-1
    if (g == 0) out[0] = 0.f;
    table[g] = 0xFFFFFFFFu;
    const int j     = g & (NPTS - 1);
    const int db    = g >> 12;                       // dir*BATCH + batch
    const int dir   = db >> 3;
    const int batch = db & 7;
    const float* colPos = dir ? A : B;
    const float* colNrm = dir ? B : A;
    const int bb = batch * CPB * NPTS;
    float qx = colPos[bb + 0*NPTS + j];
    float qy = colPos[bb + 1*NPTS + j];
    float qz = colPos[bb + 2*NPTS + j];
    float nx = colNrm[bb + 3*NPTS + j];
    float ny = colNrm[bb + 4*NPTS + j];
    float nz = colNrm[bb + 5*NPTS + j];
    float bias = fmaf(qx, qx, fmaf(qy, qy, qz * qz)) + W;
    float* cp = colpack + (size_t)g * 8;
    *reinterpret_cast<float4*>(cp)     = make_float4(qx, qy, qz, nx);
    *reinterpret_cast<float4*>(cp + 4) = make_float4(ny, nz, bias, 0.f);
}

__global__ __launch_bounds__(256, 4) void chamfer_min_kernel(
    const float* __restrict__ A, const float* __restrict__ B,
    const float* __restrict__ colpack, unsigned* __restrict__ table)
{
    const int dir   = blockIdx.z;
    const int batch = blockIdx.y;
    const int chunk = blockIdx.x % CHUNKS;
    const int rb    = blockIdx.x / CHUNKS;     // row block (2048 rows each)
    const float* rowPos = dir ? B : A;
    const float* rowNrm = dir ? A : B;
    const int bb  = batch * CPB * NPTS;
    const int tid = threadIdx.x;

    float r[8][6], m[8];
    const int rowBase = rb * 2048;
#pragma unroll
    for (int k = 0; k < 8; ++k) {
        const int row = rowBase + k*256 + tid;  // strided: coalesced channel loads
        r[k][0] = -2.f * rowPos[bb + 0*NPTS + row];
        r[k][1] = -2.f * rowPos[bb + 1*NPTS + row];
        r[k][2] = -2.f * rowPos[bb + 2*NPTS + row];
        r[k][3] = -W   * rowNrm[bb + 3*NPTS + row];
        r[k][4] = -W   * rowNrm[bb + 4*NPTS + row];
        r[k][5] = -W   * rowNrm[bb + 5*NPTS + row];
        m[k] = 3.4e38f;
    }

    // Opaque divergent 0: defeats uniformity analysis so col loads stay on the
    // VECTOR memory path (global_load_dwordx4, L1 broadcast), not s_load.
    unsigned zero;
    asm volatile("v_mov_b32 %0, 0" : "=v"(zero));
    const float* cp = colpack
        + ((size_t)(dir * BATCH + batch) * NPTS + chunk * TJ) * 8 + zero;

#pragma unroll 2
    for (int jj = 0; jj < TJ; jj += 2) {
        const float4 c0 = *reinterpret_cast<const float4*>(cp + (size_t)jj*8);
        const float4 c1 = *reinterpret_cast<const float4*>(cp + (size_t)jj*8 + 4);
        const float4 e0 = *reinterpret_cast<const float4*>(cp + (size_t)jj*8 + 8);
        const float4 e1 = *reinterpret_cast<const float4*>(cp + (size_t)jj*8 + 12);
#pragma unroll
        for (int k = 0; k < 8; ++k) {
            float d1 = fmaf(r[k][0], c0.x, c1.z);
            d1 = fmaf(r[k][1], c0.y, d1);
            d1 = fmaf(r[k][2], c0.z, d1);
            d1 = fmaf(r[k][3], c0.w, d1);
            d1 = fmaf(r[k][4], c1.x, d1);
            d1 = fmaf(r[k][5], c1.y, d1);
            float d2 = fmaf(r[k][0], e0.x, e1.z);
            d2 = fmaf(r[k][1], e0.y, d2);
            d2 = fmaf(r[k][2], e0.z, d2);
            d2 = fmaf(r[k][3], e0.w, d2);
            d2 = fmaf(r[k][4], e1.x, d2);
            d2 = fmaf(r[k][5], e1.y, d2);
            m[k] = fminf(m[k], fminf(d1, d2));  // -> v_min3_f32
        }
    }

    // Row bias |p_i|^2 = ((-2p)^2)/4 folded here (monotone add, chunk-uniform),
    // then exact cross-chunk min via u32 atomicMin on monotone keys.
    unsigned* t = table + (size_t)(dir * BATCH + batch) * NPTS;
#pragma unroll
    for (int k = 0; k < 8; ++k) {
        const float bias = 0.25f * fmaf(r[k][0], r[k][0],
                                 fmaf(r[k][1], r[k][1], r[k][2] * r[k][2]));
        atomicMin(&t[rowBase + k*256 + tid], fkey(m[k] + bias));
    }
}

__global__ __launch_bounds__(256) void sum_kernel(
    const unsigned* __restrict__ table, float* __restrict__ out)
{
    const int dir   = blockIdx.z;
    const int batch = blockIdx.y;
    const int half  = blockIdx.x;               // 2 halves of 2048 rows
    const int tid   = threadIdx.x;
    const unsigned* t = table + (size_t)(dir * BATCH + batch) * NPTS + half * 2048;

    float v = 0.f;
#pragma unroll
    for (int s = 0; s < 8; ++s)
        v += funkey(t[s * 256 + tid]);
    for (int off = 32; off; off >>= 1)
        v += __shfl_down(v, off, 64);
    __shared__ float sred[4];
    if ((tid & 63) == 0) sred[tid >> 6] = v;
    __syncthreads();
    if (tid == 0)
        atomicAdd(out, (sred[0] + sred[1] + sred[2] + sred[3]) * 0.125f); // /B
}

extern "C" void kernel_launch(void* const* d_in, const int* in_sizes, int n_in,
                              void* d_out, int out_size, void* d_ws, size_t ws_size,
                              hipStream_t stream) {
    const float* A = (const float*)d_in[0];
    const float* B = (const float*)d_in[1];
    float* out     = (float*)d_out;

    // ws layout: [ key table: 2*8*4096 u32 = 256KB ][ colpack: 2*8*4096*8 f32 = 2MB ]
    unsigned* table = (unsigned*)d_ws;
    float* colpack  = (float*)((char*)d_ws + (size_t)2 * BATCH * NPTS * sizeof(unsigned));

    prep_kernel<<<dim3(2 * BATCH * NPTS / 256), 256, 0, stream>>>(A, B, colpack, table, out);
    // 64*8*2 = 1024 blocks = 4 blocks/CU = 4 waves/SIMD
    chamfer_min_kernel<<<dim3(2 * CHUNKS, BATCH, 2), 256, 0, stream>>>(A, B, colpack, table);
    sum_kernel<<<dim3(2, BATCH, 2), 256, 0, stream>>>(table, out);
}

// Round 6
// 88.077 us; speedup vs baseline: 1.1868x; 1.1868x over previous
//
#include <hip/hip_runtime.h>

// Chamfer-with-normals, B=8, C=6 (3 pos + 3 nrm), N=4096, fp32.
// d[i][j] = aa_i + (bb_j + W) + r_i.c_j,  r=(-2p_i, -W bn_i), c=(q_j, an_j)
// (cross-indexed normals verified absmax=0 in R1-R5).
//
// R6: move the 268M-cell distance+min from the 157-TF fp32 VALU (additive
// VALU+operand-delivery bound, ~45us floor measured R3-R5) to the 2.5-PF
// matrix pipe. f16 hi/lo split with ALL FOUR cross terms makes the dot
// near-fp32-exact (rel err ~2^-22). One K=32 mfma_f32_16x16x32_f16 per
// 16x16 tile computes the ENTIRE d (both biases ride in K-slots 24-27):
//   A32 = [rh6 | rl6 | rh6 | rl6 | 1 1 ah al | 0000]   (rows)
//   B32 = [ch6 | ch6 | cl6 | cl6 | bh bl 1 1 | 0000]   (cols)
// Verified layouts (m89/m120): A[m=lane&15][k=quad*8+j], B[k=quad*8+j][n=lane&15],
// D[row=quad*4+reg][col=lane&15]. Min over cols = v_min3 fold over col-tiles
// + shfl_xor(1,2,4,8) over lane&15. RowT stored compact (16 f16) and expanded
// to the duplicated A-frag at setup (quad-dependent select).
// ws: rowT 2MB + colpack 4MB + partials 1MB = 7MB (<= proven 8MB).

constexpr int   NPTS  = 4096;
constexpr int   CPB   = 6;
constexpr int   BATCH = 8;
constexpr float W     = 0.001f;

typedef _Float16 f16x8 __attribute__((ext_vector_type(8)));
typedef float    f32x4 __attribute__((ext_vector_type(4)));

#define MFMA32(A_, B_, C_) __builtin_amdgcn_mfma_f32_16x16x32_f16((A_), (B_), (C_), 0, 0, 0)

__device__ inline void fsplit(float x, _Float16& h, _Float16& l) {
    h = (_Float16)x;
    l = (_Float16)(x - (float)h);
}

__global__ __launch_bounds__(256) void prep_kernel(
    const float* __restrict__ A, const float* __restrict__ B,
    _Float16* __restrict__ rowT, _Float16* __restrict__ colpack,
    float* __restrict__ out)
{
    const int g = blockIdx.x * 256 + threadIdx.x;   // 0 .. 65535
    if (g == 0) out[0] = 0.f;
    const int j = g & (NPTS - 1), bd = g >> 12, dir = bd >> 3, batch = bd & 7;
    const int bb = batch * CPB * NPTS;
    const float* rowPos = dir ? B : A;
    const float* rowNrm = dir ? A : B;
    const float* colPos = dir ? A : B;
    const float* colNrm = dir ? B : A;

    // ---- row record: compact 16 f16 = [rh0-5, rl0-5, 1, ah, al, 0]
    const float p0 = rowPos[bb + 0*NPTS + j], p1 = rowPos[bb + 1*NPTS + j],
                p2 = rowPos[bb + 2*NPTS + j];
    const float rn0 = rowNrm[bb + 3*NPTS + j], rn1 = rowNrm[bb + 4*NPTS + j],
                rn2 = rowNrm[bb + 5*NPTS + j];
    const float r6[6] = {-2.f*p0, -2.f*p1, -2.f*p2, -W*rn0, -W*rn1, -W*rn2};
    const float aa = fmaf(p0, p0, fmaf(p1, p1, p2*p2));
    _Float16 rh[6], rl[6], ah, al;
#pragma unroll
    for (int c = 0; c < 6; ++c) fsplit(r6[c], rh[c], rl[c]);
    fsplit(aa, ah, al);
    const _Float16 one = (_Float16)1.f, zz = (_Float16)0.f;
    f16x8 r0 = {rh[0], rh[1], rh[2], rh[3], rh[4], rh[5], rl[0], rl[1]};
    f16x8 r1 = {rl[2], rl[3], rl[4], rl[5], one, ah, al, zz};
    *(f16x8*)(rowT + (size_t)g * 16)     = r0;
    *(f16x8*)(rowT + (size_t)g * 16 + 8) = r1;

    // ---- col record: full B32 = [ch6 | ch6 | cl6 | cl6 | bh bl 1 1 | 0000]
    const float q0 = colPos[bb + 0*NPTS + j], q1 = colPos[bb + 1*NPTS + j],
                q2 = colPos[bb + 2*NPTS + j];
    const float cn0 = colNrm[bb + 3*NPTS + j], cn1 = colNrm[bb + 4*NPTS + j],
                cn2 = colNrm[bb + 5*NPTS + j];
    const float c6[6] = {q0, q1, q2, cn0, cn1, cn2};
    const float bias = fmaf(q0, q0, fmaf(q1, q1, q2*q2)) + W;
    _Float16 ch[6], cl[6], bh, bl;
#pragma unroll
    for (int c = 0; c < 6; ++c) fsplit(c6[c], ch[c], cl[c]);
    fsplit(bias, bh, bl);
    f16x8 v0 = {ch[0], ch[1], ch[2], ch[3], ch[4], ch[5], ch[0], ch[1]};
    f16x8 v1 = {ch[2], ch[3], ch[4], ch[5], cl[0], cl[1], cl[2], cl[3]};
    f16x8 v2 = {cl[4], cl[5], cl[0], cl[1], cl[2], cl[3], cl[4], cl[5]};
    f16x8 v3 = {bh, bl, one, one, zz, zz, zz, zz};
    _Float16* cp = colpack + (size_t)g * 32;
    *(f16x8*)(cp)      = v0;
    *(f16x8*)(cp + 8)  = v1;
    *(f16x8*)(cp + 16) = v2;
    *(f16x8*)(cp + 24) = v3;
}

// Grid: x = 8 rowgroups(512 rows) * 4 colsplits(1024 cols), y = batch, z = dir.
// 512 blocks = 2/CU; 256 thr = 4 waves; wave owns 8 row-tiles, sweeps block cols.
__global__ __launch_bounds__(256, 2) void chamfer_mfma_kernel(
    const _Float16* __restrict__ rowT, const _Float16* __restrict__ colpack,
    float* __restrict__ partial)
{
    const int dir = blockIdx.z, batch = blockIdx.y, bd = dir * BATCH + batch;
    const int rg = blockIdx.x >> 2, s = blockIdx.x & 3;
    const int tid = threadIdx.x, w = tid >> 6, lane = tid & 63;
    const int quad = lane >> 4, l16 = lane & 15;

    __shared__ _Float16 lds[512 * 32];   // 512 cols x 64B = 32KB

    // A-frags: expand compact row record to duplicated A32 slots (quad-select).
    f16x8 a[8];
    {
        const _Float16* rb = rowT + ((size_t)bd * NPTS + rg * 512) * 16;
#pragma unroll
        for (int rt = 0; rt < 8; ++rt) {
            const int row = (w * 8 + rt) * 16 + l16;
            const f16x8 rec0 = *(const f16x8*)(rb + (size_t)row * 16);
            const f16x8 rec1 = *(const f16x8*)(rb + (size_t)row * 16 + 8);
            f16x8 af;
            if (quad == 0)      af = rec0;                                   // slots 0-7
            else if (quad == 1) af = f16x8{rec1[0], rec1[1], rec1[2], rec1[3],
                                           rec0[0], rec0[1], rec0[2], rec0[3]}; // 8-15
            else if (quad == 2) af = f16x8{rec0[4], rec0[5], rec0[6], rec0[7],
                                           rec1[0], rec1[1], rec1[2], rec1[3]}; // 16-23
            else                af = f16x8{rec1[4], rec1[4], rec1[5], rec1[6],
                                           (_Float16)0.f, (_Float16)0.f,
                                           (_Float16)0.f, (_Float16)0.f};       // 24-31
            a[rt] = af;
        }
    }

    float m[8][4];
#pragma unroll
    for (int rt = 0; rt < 8; ++rt)
#pragma unroll
        for (int r_ = 0; r_ < 4; ++r_) m[rt][r_] = 3.4e38f;

    const _Float16* cpb = colpack + ((size_t)bd * NPTS + s * 1024) * 32;
    const f32x4 z = {0.f, 0.f, 0.f, 0.f};

    for (int ph = 0; ph < 2; ++ph) {
        if (ph) __syncthreads();
        {   // stage 512 cols (32KB), fully coalesced uint4 copy
            const uint4* src = (const uint4*)(cpb + (size_t)ph * 512 * 32);
            uint4* dst = (uint4*)lds;
#pragma unroll
            for (int i = 0; i < 8; ++i) dst[tid + i * 256] = src[tid + i * 256];
        }
        __syncthreads();
        for (int ct = 0; ct < 32; ct += 2) {
            const f16x8 b0 = *(const f16x8*)&lds[(ct * 16 + l16) * 32 + quad * 8];
            const f16x8 b1 = *(const f16x8*)&lds[((ct + 1) * 16 + l16) * 32 + quad * 8];
#pragma unroll
            for (int rt = 0; rt < 8; ++rt) {
                f32x4 acc0 = MFMA32(a[rt], b0, z);
                f32x4 acc1 = MFMA32(a[rt], b1, z);
#pragma unroll
                for (int r_ = 0; r_ < 4; ++r_)
                    m[rt][r_] = fminf(m[rt][r_], fminf(acc0[r_], acc1[r_]));  // v_min3
            }
        }
    }

    // finish col-min: reduce over lane&15 (cols) via shfl_xor
#pragma unroll
    for (int rt = 0; rt < 8; ++rt)
#pragma unroll
        for (int r_ = 0; r_ < 4; ++r_) {
            float v = m[rt][r_];
            v = fminf(v, __shfl_xor(v, 1));
            v = fminf(v, __shfl_xor(v, 2));
            v = fminf(v, __shfl_xor(v, 4));
            v = fminf(v, __shfl_xor(v, 8));
            m[rt][r_] = v;
        }
    if (l16 == 0) {
        float* pb = partial + ((size_t)(s * 16 + bd)) * NPTS + rg * 512;
#pragma unroll
        for (int rt = 0; rt < 8; ++rt) {
            const int rb_ = (w * 8 + rt) * 16 + quad * 4;   // D row = quad*4+reg
            *(float4*)(pb + rb_) = make_float4(m[rt][0], m[rt][1], m[rt][2], m[rt][3]);
        }
    }
}

__global__ __launch_bounds__(256) void reduce_kernel(
    const float* __restrict__ partial, float* __restrict__ out)
{
    const int g = blockIdx.x * 256 + threadIdx.x;   // 0 .. 65535
    const int bd = g >> 12, row = g & (NPTS - 1);
    float v = partial[(size_t)(0 * 16 + bd) * NPTS + row];
    v = fminf(v, partial[(size_t)(1 * 16 + bd) * NPTS + row]);
    v = fminf(v, partial[(size_t)(2 * 16 + bd) * NPTS + row]);
    v = fminf(v, partial[(size_t)(3 * 16 + bd) * NPTS + row]);
    for (int off = 32; off; off >>= 1)
        v += __shfl_down(v, off, 64);
    __shared__ float sred[4];
    if ((threadIdx.x & 63) == 0) sred[threadIdx.x >> 6] = v;
    __syncthreads();
    if (threadIdx.x == 0)
        atomicAdd(out, (sred[0] + sred[1] + sred[2] + sred[3]) * 0.125f);  // /B
}

extern "C" void kernel_launch(void* const* d_in, const int* in_sizes, int n_in,
                              void* d_out, int out_size, void* d_ws, size_t ws_size,
                              hipStream_t stream) {
    const float* A = (const float*)d_in[0];
    const float* B = (const float*)d_in[1];
    float* out = (float*)d_out;

    // ws: [rowT 2MB][colpack 4MB][partial 1MB] = 7MB (proven ws >= 8MB in R4)
    _Float16* rowT    = (_Float16*)d_ws;
    _Float16* colpack = rowT + (size_t)2 * BATCH * NPTS * 16;
    float*    partial = (float*)((char*)d_ws + (size_t)6 * 1024 * 1024);

    prep_kernel<<<dim3(2 * BATCH * NPTS / 256), 256, 0, stream>>>(A, B, rowT, colpack, out);
    chamfer_mfma_kernel<<<dim3(32, BATCH, 2), 256, 0, stream>>>(rowT, colpack, partial);
    reduce_kernel<<<dim3(2 * BATCH * NPTS / 256), 256, 0, stream>>>(partial, out);
}

// Round 7
// 77.126 us; speedup vs baseline: 1.3553x; 1.1420x over previous
//
#include <hip/hip_runtime.h>

// Chamfer-with-normals, B=8, C=6 (3 pos + 3 nrm), N=4096, fp32.
// d[i][j] = aa_i + (bb_j + W) + r_i.c_j,  r=(-2p_i, -W bn_i), c=(q_j, an_j)
// (cross-indexed normals; R6 MFMA formulation verified absmax=0).
//
// R7: timed budget analysis — the harness's 0xAA re-poison of d_ws is a fixed
// 43us fillBuffer INSIDE the timed path (top-5 all fills, 256MiB WRITE_SIZE);
// controllable time in R6 was only ~45us across 3 kernels + 3 gaps. So: fuse
// prep into the MFMA kernel (col/row records computed inline; x8 per-block
// redundancy is ~800cyc/CU), 2 dispatches total, no 6MB record round-trip.
// Single LDS phase: 64KB = full 1024-col split in [k-plane][col] interleaved
// layout (ds_write/ds_read both consecutive-16B, conflict-free), ONE barrier.
// rt=8 rows/wave keeps LDS reads (512KB/CU ~5k cyc) balanced vs MFMA (4.9k
// cyc/SIMD). One K=32 mfma_f32_16x16x32_f16 per 16x16 tile computes full d:
//   A32 = [rh6|rl6|rh6|rl6| 1 1 ah al |0000], B32 = [ch6|ch6|cl6|cl6| bh bl 1 1 |0000]
// Layouts m89/m120-verified; D[row=quad*4+reg][col=lane&15].

constexpr int   NPTS  = 4096;
constexpr int   CPB   = 6;
constexpr int   BATCH = 8;
constexpr float W     = 0.001f;

typedef _Float16 f16x8 __attribute__((ext_vector_type(8)));
typedef float    f32x4 __attribute__((ext_vector_type(4)));

#define MFMA32(A_, B_, C_) __builtin_amdgcn_mfma_f32_16x16x32_f16((A_), (B_), (C_), 0, 0, 0)

__device__ inline void fsplit(float x, _Float16& h, _Float16& l) {
    h = (_Float16)x;
    l = (_Float16)(x - (float)h);
}

// Grid: x = 8 rowgroups(512 rows) * 4 colsplits(1024 cols), y = batch, z = dir.
// 512 blocks = 2/CU; 256 thr = 4 waves; wave owns 8 row-tiles, sweeps 64 col-tiles.
__global__ __launch_bounds__(256, 2) void chamfer_fused_kernel(
    const float* __restrict__ A, const float* __restrict__ B,
    float* __restrict__ partial, float* __restrict__ out)
{
    const int dir = blockIdx.z, batch = blockIdx.y, bd = dir * BATCH + batch;
    const int rg = blockIdx.x >> 2, s = blockIdx.x & 3;
    const int tid = threadIdx.x, w = tid >> 6, lane = tid & 63;
    const int quad = lane >> 4, l16 = lane & 15;
    const float* rowPos = dir ? B : A;
    const float* rowNrm = dir ? A : B;
    const float* colPos = dir ? A : B;
    const float* colNrm = dir ? B : A;
    const int bb = batch * CPB * NPTS;
    const _Float16 one = (_Float16)1.f, zz = (_Float16)0.f;

    if (blockIdx.x == 0 && blockIdx.y == 0 && blockIdx.z == 0 && tid == 0)
        out[0] = 0.f;                       // ordered before reduce's atomics

    // [k-plane][col][8 f16]: plane k at k*8192 f16 (16KB); both LDS write and
    // read are lane-consecutive 16B bursts (conflict-free b128 pattern).
    __shared__ alignas(16) _Float16 lds[4 * 1024 * 8];   // 64 KB

    // ---- stage this block's 1024 cols inline (4 cols per thread)
#pragma unroll
    for (int p = 0; p < 4; ++p) {
        const int j  = p * 256 + tid;       // col within split
        const int cj = s * 1024 + j;
        const float q0 = colPos[bb + 0*NPTS + cj], q1 = colPos[bb + 1*NPTS + cj],
                    q2 = colPos[bb + 2*NPTS + cj];
        const float n0 = colNrm[bb + 3*NPTS + cj], n1 = colNrm[bb + 4*NPTS + cj],
                    n2 = colNrm[bb + 5*NPTS + cj];
        const float c6[6] = {q0, q1, q2, n0, n1, n2};
        const float bias = fmaf(q0, q0, fmaf(q1, q1, q2*q2)) + W;
        _Float16 ch[6], cl[6], bh, bl;
#pragma unroll
        for (int c = 0; c < 6; ++c) fsplit(c6[c], ch[c], cl[c]);
        fsplit(bias, bh, bl);
        f16x8 v0 = {ch[0], ch[1], ch[2], ch[3], ch[4], ch[5], ch[0], ch[1]};
        f16x8 v1 = {ch[2], ch[3], ch[4], ch[5], cl[0], cl[1], cl[2], cl[3]};
        f16x8 v2 = {cl[4], cl[5], cl[0], cl[1], cl[2], cl[3], cl[4], cl[5]};
        f16x8 v3 = {bh, bl, one, one, zz, zz, zz, zz};
        *(f16x8*)&lds[0 * 8192 + j * 8] = v0;
        *(f16x8*)&lds[1 * 8192 + j * 8] = v1;
        *(f16x8*)&lds[2 * 8192 + j * 8] = v2;
        *(f16x8*)&lds[3 * 8192 + j * 8] = v3;
    }

    // ---- A-frags inline (quad-dependent slot expansion, verified in R6)
    f16x8 a[8];
#pragma unroll
    for (int rt = 0; rt < 8; ++rt) {
        const int row = rg * 512 + (w * 8 + rt) * 16 + l16;
        const float p0 = rowPos[bb + 0*NPTS + row], p1 = rowPos[bb + 1*NPTS + row],
                    p2 = rowPos[bb + 2*NPTS + row];
        const float rn0 = rowNrm[bb + 3*NPTS + row], rn1 = rowNrm[bb + 4*NPTS + row],
                    rn2 = rowNrm[bb + 5*NPTS + row];
        const float r6[6] = {-2.f*p0, -2.f*p1, -2.f*p2, -W*rn0, -W*rn1, -W*rn2};
        const float aa = fmaf(p0, p0, fmaf(p1, p1, p2*p2));
        _Float16 rh[6], rl[6], ah, al;
#pragma unroll
        for (int c = 0; c < 6; ++c) fsplit(r6[c], rh[c], rl[c]);
        fsplit(aa, ah, al);
        f16x8 af;
        if (quad == 0)      af = f16x8{rh[0], rh[1], rh[2], rh[3], rh[4], rh[5], rl[0], rl[1]};
        else if (quad == 1) af = f16x8{rl[2], rl[3], rl[4], rl[5], rh[0], rh[1], rh[2], rh[3]};
        else if (quad == 2) af = f16x8{rh[4], rh[5], rl[0], rl[1], rl[2], rl[3], rl[4], rl[5]};
        else                af = f16x8{one, one, ah, al, zz, zz, zz, zz};
        a[rt] = af;
    }

    float m[8][4];
#pragma unroll
    for (int rt = 0; rt < 8; ++rt)
#pragma unroll
        for (int r_ = 0; r_ < 4; ++r_) m[rt][r_] = 3.4e38f;

    __syncthreads();                        // the kernel's only barrier

    const _Float16* lq = &lds[quad * 8192];
    const f32x4 z = {0.f, 0.f, 0.f, 0.f};
    for (int ct = 0; ct < 64; ct += 2) {
        const f16x8 b0 = *(const f16x8*)&lq[(ct * 16 + l16) * 8];
        const f16x8 b1 = *(const f16x8*)&lq[((ct + 1) * 16 + l16) * 8];
#pragma unroll
        for (int rt = 0; rt < 8; ++rt) {
            f32x4 acc0 = MFMA32(a[rt], b0, z);
            f32x4 acc1 = MFMA32(a[rt], b1, z);
#pragma unroll
            for (int r_ = 0; r_ < 4; ++r_)
                m[rt][r_] = fminf(m[rt][r_], fminf(acc0[r_], acc1[r_]));  // v_min3
        }
    }

    // finish col-min within tile: reduce over lane&15 (cols) via shfl_xor
#pragma unroll
    for (int rt = 0; rt < 8; ++rt)
#pragma unroll
        for (int r_ = 0; r_ < 4; ++r_) {
            float v = m[rt][r_];
            v = fminf(v, __shfl_xor(v, 1));
            v = fminf(v, __shfl_xor(v, 2));
            v = fminf(v, __shfl_xor(v, 4));
            v = fminf(v, __shfl_xor(v, 8));
            m[rt][r_] = v;
        }
    if (l16 == 0) {
        float* pb = partial + ((size_t)(s * 16 + bd)) * NPTS + rg * 512;
#pragma unroll
        for (int rt = 0; rt < 8; ++rt) {
            const int rb_ = (w * 8 + rt) * 16 + quad * 4;   // D row = quad*4+reg
            *(float4*)(pb + rb_) = make_float4(m[rt][0], m[rt][1], m[rt][2], m[rt][3]);
        }
    }
}

__global__ __launch_bounds__(256) void reduce_kernel(
    const float* __restrict__ partial, float* __restrict__ out)
{
    const int g = blockIdx.x * 256 + threadIdx.x;   // 0 .. 65535
    const int bd = g >> 12, row = g & (NPTS - 1);
    float v = partial[(size_t)(0 * 16 + bd) * NPTS + row];
    v = fminf(v, partial[(size_t)(1 * 16 + bd) * NPTS + row]);
    v = fminf(v, partial[(size_t)(2 * 16 + bd) * NPTS + row]);
    v = fminf(v, partial[(size_t)(3 * 16 + bd) * NPTS + row]);
    for (int off = 32; off; off >>= 1)
        v += __shfl_down(v, off, 64);
    __shared__ float sred[4];
    if ((threadIdx.x & 63) == 0) sred[threadIdx.x >> 6] = v;
    __syncthreads();
    if (threadIdx.x == 0)
        atomicAdd(out, (sred[0] + sred[1] + sred[2] + sred[3]) * 0.125f);  // /B
}

extern "C" void kernel_launch(void* const* d_in, const int* in_sizes, int n_in,
                              void* d_out, int out_size, void* d_ws, size_t ws_size,
                              hipStream_t stream) {
    const float* A = (const float*)d_in[0];
    const float* B = (const float*)d_in[1];
    float* out     = (float*)d_out;
    float* partial = (float*)d_ws;          // 4 splits x 16 bd x 4096 f32 = 1 MB

    chamfer_fused_kernel<<<dim3(32, BATCH, 2), 256, 0, stream>>>(A, B, partial, out);
    reduce_kernel<<<dim3(2 * BATCH * NPTS / 256), 256, 0, stream>>>(partial, out);
}